// Round 1
// baseline (1370.259 us; speedup 1.0000x reference)
//
#include <hip/hip_runtime.h>
#include <hip/hip_bf16.h>

// Problem constants
#define PN 16384
#define PZ 100
#define PE 400
#define PM0 4000
#define PM1 2000

// ---------------------------------------------------------------------------
// K1: topic[z][m] = sum_e beta[z][e] * alpha[m][e]   (Z x M), f32
// grid.x = m-tile (64 cols), grid.y = z-group (20 z each, 5 groups)
// block 256 = 64 m-lanes x 4 z-threads, each z-thread does 5 z values
// ---------------------------------------------------------------------------
__global__ __launch_bounds__(256) void topic_kernel(
    const float* __restrict__ alpha, const float* __restrict__ beta,
    float* __restrict__ topic, int M)
{
    __shared__ float sA[64][201];  // e-chunk of 200, pad 201 (odd -> conflict-free)
    const int tid = threadIdx.x;
    const int ml = tid & 63;
    const int zt = tid >> 6;
    const int m0 = blockIdx.x * 64;
    const int z0 = blockIdx.y * 20 + zt * 5;

    float acc[5] = {0.f, 0.f, 0.f, 0.f, 0.f};

    for (int ec = 0; ec < 2; ++ec) {
        // stage alpha tile: 64 rows x 200 e
        #pragma unroll
        for (int l = 0; l < 50; ++l) {   // 64*200/256
            int idx = tid + l * 256;
            int mr = idx / 200;
            int e  = idx - mr * 200;
            int m  = m0 + mr;
            sA[mr][e] = (m < M) ? alpha[(size_t)m * PE + ec * 200 + e] : 0.f;
        }
        __syncthreads();

        const float* bz = beta + (size_t)z0 * PE + ec * 200;  // wave-uniform
        #pragma unroll 4
        for (int e = 0; e < 200; ++e) {
            float a = sA[ml][e];
            #pragma unroll
            for (int zi = 0; zi < 5; ++zi)
                acc[zi] = fmaf(bz[zi * PE + e], a, acc[zi]);
        }
        __syncthreads();
    }

    int m = m0 + ml;
    if (m < M) {
        #pragma unroll
        for (int zi = 0; zi < 5; ++zi)
            topic[(size_t)(z0 + zi) * M + m] = acc[zi];
    }
}

// ---------------------------------------------------------------------------
// K2: logits = theta @ topic + bias[dom], write raw logits to out,
//     plus per-(row, col-tile) partial max and sum(exp(x - max)).
// Tile: 128 rows x 128 cols, 256 threads, 8x8 per-thread register tile.
// K staged in 2 chunks of 50 to stay under 64 KB static LDS.
// ---------------------------------------------------------------------------
__global__ __launch_bounds__(256) void gemm_lse_kernel(
    const float* __restrict__ theta, const float* __restrict__ topic,
    const float* __restrict__ bias, const int* __restrict__ dom,
    float* __restrict__ out, float* __restrict__ pmax, float* __restrict__ psum,
    int M, int ntiles)
{
    __shared__ float sTh[50][132];  // theta transposed [k][row], pad 132 (16B-aligned rows)
    __shared__ float sTp[50][128];  // topic [k][col]

    const int tid = threadIdx.x;
    const int tc = tid & 15;       // col group 0..15
    const int tr = tid >> 4;       // row group 0..15
    const int m0 = blockIdx.x * 128;
    const int n0 = blockIdx.y * 128;

    float acc[8][8];
    #pragma unroll
    for (int i = 0; i < 8; ++i)
        #pragma unroll
        for (int j = 0; j < 8; ++j) acc[i][j] = 0.f;

    for (int kc = 0; kc < 2; ++kc) {
        // stage theta chunk, transposed: 128 rows x 50 k
        #pragma unroll
        for (int l = 0; l < 25; ++l) {   // 128*50/256
            int idx = tid + l * 256;
            int nl = idx / 50;
            int kl = idx - nl * 50;
            sTh[kl][nl] = theta[(size_t)(n0 + nl) * PZ + kc * 50 + kl];
        }
        // stage topic chunk: 50 k x 128 cols
        #pragma unroll
        for (int l = 0; l < 25; ++l) {
            int idx = tid + l * 256;
            int zl = idx >> 7;
            int ml = idx & 127;
            int m = m0 + ml;
            sTp[zl][ml] = (m < M) ? topic[(size_t)(kc * 50 + zl) * M + m] : 0.f;
        }
        __syncthreads();

        #pragma unroll 5
        for (int k = 0; k < 50; ++k) {
            float4 A0 = *(const float4*)&sTh[k][tr * 4];
            float4 A1 = *(const float4*)&sTh[k][64 + tr * 4];
            float4 B0 = *(const float4*)&sTp[k][tc * 4];
            float4 B1 = *(const float4*)&sTp[k][64 + tc * 4];
            float a[8] = {A0.x, A0.y, A0.z, A0.w, A1.x, A1.y, A1.z, A1.w};
            float b[8] = {B0.x, B0.y, B0.z, B0.w, B1.x, B1.y, B1.z, B1.w};
            #pragma unroll
            for (int i = 0; i < 8; ++i)
                #pragma unroll
                for (int j = 0; j < 8; ++j)
                    acc[i][j] = fmaf(a[i], b[j], acc[i][j]);
        }
        __syncthreads();
    }

    // column indices + validity (4000 and 2000 are multiples of 4 -> float4-granular)
    int cols[8];
    bool cv[8];
    #pragma unroll
    for (int j = 0; j < 8; ++j) {
        int c = m0 + ((j < 4) ? (tc * 4 + j) : (64 + tc * 4 + (j - 4)));
        cols[j] = c;
        cv[j] = (c < M);
    }

    // epilogue per row: bias add, tile max/sumexp partials, raw logit store
    #pragma unroll
    for (int i = 0; i < 8; ++i) {
        int r = (i < 4) ? (tr * 4 + i) : (64 + tr * 4 + (i - 4));
        int n = n0 + r;
        int d = dom[n];
        const float* bp = bias + (size_t)d * M;

        #pragma unroll
        for (int j = 0; j < 8; ++j)
            if (cv[j]) acc[i][j] += bp[cols[j]];

        float mx = -3.0e38f;
        #pragma unroll
        for (int j = 0; j < 8; ++j)
            if (cv[j]) mx = fmaxf(mx, acc[i][j]);
        #pragma unroll
        for (int off = 1; off < 16; off <<= 1)
            mx = fmaxf(mx, __shfl_xor(mx, off, 16));

        float sm = 0.f;
        #pragma unroll
        for (int j = 0; j < 8; ++j)
            if (cv[j]) sm += __expf(acc[i][j] - mx);
        #pragma unroll
        for (int off = 1; off < 16; off <<= 1)
            sm += __shfl_xor(sm, off, 16);

        if (tc == 0) {
            pmax[(size_t)n * ntiles + blockIdx.x] = mx;
            psum[(size_t)n * ntiles + blockIdx.x] = sm;
        }

        if (cv[0]) {
            float4 v = make_float4(acc[i][0], acc[i][1], acc[i][2], acc[i][3]);
            *(float4*)&out[(size_t)n * M + cols[0]] = v;
        }
        if (cv[4]) {
            float4 v = make_float4(acc[i][4], acc[i][5], acc[i][6], acc[i][7]);
            *(float4*)&out[(size_t)n * M + cols[4]] = v;
        }
    }
}

// ---------------------------------------------------------------------------
// K3: reduce per-tile partials -> per-row LSE = max + log(sum)
// block 256 = 4 waves, 1 wave per row; lanes 0..T-1 hold tiles
// ---------------------------------------------------------------------------
__global__ __launch_bounds__(256) void lse_kernel(
    const float* __restrict__ pmax, const float* __restrict__ psum,
    float* __restrict__ lse, int T)
{
    const int lane = threadIdx.x & 63;
    const int w = threadIdx.x >> 6;
    const int n = blockIdx.x * 4 + w;

    float pm = (lane < T) ? pmax[(size_t)n * T + lane] : -3.0e38f;
    float ps = (lane < T) ? psum[(size_t)n * T + lane] : 0.f;

    float mx = pm;
    #pragma unroll
    for (int off = 16; off; off >>= 1)
        mx = fmaxf(mx, __shfl_xor(mx, off, 32));

    float s = ps * __expf(pm - mx);  // lane>=T: 0 * exp(0) = 0
    #pragma unroll
    for (int off = 16; off; off >>= 1)
        s += __shfl_xor(s, off, 32);

    if (lane == 0) lse[n] = mx + logf(s);
}

// ---------------------------------------------------------------------------
// K4: out[n][m] -= lse[n]   (float4 grid-stride)
// ---------------------------------------------------------------------------
__global__ __launch_bounds__(256) void fixup_kernel(
    float4* __restrict__ p, const float* __restrict__ lse, int row4, int n4)
{
    int stride = gridDim.x * blockDim.x;
    for (int i = blockIdx.x * blockDim.x + threadIdx.x; i < n4; i += stride) {
        int row = i / row4;
        float o = lse[row];
        float4 v = p[i];
        v.x -= o; v.y -= o; v.z -= o; v.w -= o;
        p[i] = v;
    }
}

// ---------------------------------------------------------------------------
extern "C" void kernel_launch(void* const* d_in, const int* in_sizes, int n_in,
                              void* d_out, int out_size, void* d_ws, size_t ws_size,
                              hipStream_t stream) {
    const float* theta  = (const float*)d_in[0];
    const float* alpha0 = (const float*)d_in[1];
    const float* alpha1 = (const float*)d_in[2];
    const float* beta   = (const float*)d_in[3];
    const float* bias0  = (const float*)d_in[4];
    const float* bias1  = (const float*)d_in[5];
    const int*   dom    = (const int*)d_in[6];

    float* out0 = (float*)d_out;
    float* out1 = out0 + (size_t)PN * PM0;

    float* ws = (float*)d_ws;
    float* topic0 = ws;                    // 100*4000 = 400000
    float* topic1 = topic0 + 400000;       // 100*2000 = 200000
    float* pmax0  = topic1 + 200000;       // 16384*32 = 524288
    float* psum0  = pmax0 + 524288;
    float* pmax1  = psum0 + 524288;        // 16384*16 = 262144
    float* psum1  = pmax1 + 262144;
    float* lse0   = psum1 + 262144;        // 16384
    float* lse1   = lse0 + PN;             // 16384
    // total ~2.21M floats = 8.9 MB of ws

    // topics
    topic_kernel<<<dim3(63, 5), 256, 0, stream>>>(alpha0, beta, topic0, PM0);
    topic_kernel<<<dim3(32, 5), 256, 0, stream>>>(alpha1, beta, topic1, PM1);

    // main GEMM + partial LSE + raw logit store
    gemm_lse_kernel<<<dim3(32, 128), 256, 0, stream>>>(
        theta, topic0, bias0, dom, out0, pmax0, psum0, PM0, 32);
    gemm_lse_kernel<<<dim3(16, 128), 256, 0, stream>>>(
        theta, topic1, bias1, dom, out1, pmax1, psum1, PM1, 16);

    // per-row LSE
    lse_kernel<<<dim3(PN / 4), 256, 0, stream>>>(pmax0, psum0, lse0, 32);
    lse_kernel<<<dim3(PN / 4), 256, 0, stream>>>(pmax1, psum1, lse1, 16);

    // subtract LSE
    fixup_kernel<<<2048, 256, 0, stream>>>((float4*)out0, lse0, PM0 / 4, PN * (PM0 / 4));
    fixup_kernel<<<2048, 256, 0, stream>>>((float4*)out1, lse1, PM1 / 4, PN * (PM1 / 4));
}

// Round 2
// 544.702 us; speedup vs baseline: 2.5156x; 2.5156x over previous
//
#include <hip/hip_runtime.h>
#include <hip/hip_bf16.h>

// Problem constants
#define PN 16384
#define PZ 100
#define PE 400
#define PM0 4000
#define PM1 2000
#define KP 256          // packed K: [0,100)=hi, [100,200)=lo/dup, rest zero

typedef __attribute__((ext_vector_type(8))) short short8v;
typedef __attribute__((ext_vector_type(4))) short short4v;
typedef __attribute__((ext_vector_type(4))) float floatx4;

__device__ __forceinline__ unsigned short f2bf(float x) {
    union { float f; unsigned int u; } v; v.f = x;
    unsigned int r = (v.u + 0x7FFFu + ((v.u >> 16) & 1u)) >> 16;
    return (unsigned short)r;
}
__device__ __forceinline__ float bf2f(unsigned short h) {
    union { float f; unsigned int u; } v; v.u = ((unsigned int)h) << 16; return v.f;
}

__device__ __forceinline__ void gload16(const void* g, void* l) {
    __builtin_amdgcn_global_load_lds(
        (const __attribute__((address_space(1))) void*)g,
        (__attribute__((address_space(3))) void*)l, 16, 0, 0);
}

// ---------------------------------------------------------------------------
// K1: topic[z][m] = sum_e beta[z][e] * alpha[m][e]   (Z x M), f32  (unchanged)
// ---------------------------------------------------------------------------
__global__ __launch_bounds__(256) void topic_kernel(
    const float* __restrict__ alpha, const float* __restrict__ beta,
    float* __restrict__ topic, int M)
{
    __shared__ float sA[64][201];
    const int tid = threadIdx.x;
    const int ml = tid & 63;
    const int zt = tid >> 6;
    const int m0 = blockIdx.x * 64;
    const int z0 = blockIdx.y * 20 + zt * 5;

    float acc[5] = {0.f, 0.f, 0.f, 0.f, 0.f};

    for (int ec = 0; ec < 2; ++ec) {
        #pragma unroll
        for (int l = 0; l < 50; ++l) {
            int idx = tid + l * 256;
            int mr = idx / 200;
            int e  = idx - mr * 200;
            int m  = m0 + mr;
            sA[mr][e] = (m < M) ? alpha[(size_t)m * PE + ec * 200 + e] : 0.f;
        }
        __syncthreads();
        const float* bz = beta + (size_t)z0 * PE + ec * 200;
        #pragma unroll 4
        for (int e = 0; e < 200; ++e) {
            float a = sA[ml][e];
            #pragma unroll
            for (int zi = 0; zi < 5; ++zi)
                acc[zi] = fmaf(bz[zi * PE + e], a, acc[zi]);
        }
        __syncthreads();
    }
    int m = m0 + ml;
    if (m < M) {
        #pragma unroll
        for (int zi = 0; zi < 5; ++zi)
            topic[(size_t)(z0 + zi) * M + m] = acc[zi];
    }
}

// ---------------------------------------------------------------------------
// prep: A2[n][k] bf16 : k<100 -> bf16(theta), 100..199 -> bf16(theta - hi), else 0
// ---------------------------------------------------------------------------
__global__ __launch_bounds__(256) void prep_theta_kernel(
    const float* __restrict__ theta, unsigned short* __restrict__ A2)
{
    const int n = blockIdx.x;
    const int k = threadIdx.x;
    unsigned short h = 0;
    if (k < 100) {
        h = f2bf(theta[(size_t)n * PZ + k]);
    } else if (k < 200) {
        float t = theta[(size_t)n * PZ + (k - 100)];
        h = f2bf(t - bf2f(f2bf(t)));
    }
    A2[(size_t)n * KP + k] = h;
}

// ---------------------------------------------------------------------------
// prep: B2T[m][k] bf16 : k<200 -> bf16(topic[k%100][m]) (duplicated), else 0
// rows m in [M, Mpad) are zero
// ---------------------------------------------------------------------------
__global__ __launch_bounds__(256) void prep_topicT_kernel(
    const float* __restrict__ topic, unsigned short* __restrict__ B2T, int M)
{
    const int m = blockIdx.x;
    const int k = threadIdx.x;
    unsigned short h = 0;
    if (m < M && k < 200) {
        int z = (k < 100) ? k : (k - 100);
        h = f2bf(topic[(size_t)z * M + m]);
    }
    B2T[(size_t)m * KP + k] = h;
}

// ---------------------------------------------------------------------------
// Main MFMA pass. 128x128 tile, 4 waves (2x2), 16x16x32 bf16, K=256 in 4 steps.
// WRITE==0: emit per-(row, 64-col-chunk) max / sumexp partials.
// WRITE==1: out[n][m] = logit - lse[n].
// ---------------------------------------------------------------------------
template<int WRITE>
__global__ __launch_bounds__(256) void mfma_pass(
    const unsigned short* __restrict__ A2,   // [PN][KP]
    const unsigned short* __restrict__ B2T,  // [Mpad][KP]
    const float* __restrict__ bias,          // [D][M]
    const int* __restrict__ dom,
    const float* __restrict__ lse,
    float* __restrict__ out,
    float* __restrict__ pmax, float* __restrict__ psum,
    int M, int PT)
{
    __shared__ __align__(1024) unsigned short sA[128 * 64];  // 16 KB, rows of 128 B
    __shared__ __align__(1024) unsigned short sB[128 * 64];  // 16 KB

    const int tid  = threadIdx.x;
    const int w    = tid >> 6;
    const int ll   = tid & 63;
    const int wrow = (w & 1) * 64;
    const int wcol = (w >> 1) * 64;
    const int g    = ll >> 4;      // 0..3
    const int c    = ll & 15;      // 0..15
    const int n0   = blockIdx.y * 128;
    const int m0   = blockIdx.x * 128;

    floatx4 acc[4][4];
    #pragma unroll
    for (int i = 0; i < 4; ++i)
        #pragma unroll
        for (int j = 0; j < 4; ++j)
            acc[i][j] = (floatx4){0.f, 0.f, 0.f, 0.f};

    // staging lane decomposition: per instr 1024 B = 8 rows of 128 B
    const int srow_l = ll >> 3;        // 0..7 row within instr
    const int sslot  = ll & 7;         // dest 16B slot within row

    for (int kc = 0; kc < 4; ++kc) {
        #pragma unroll
        for (int it = 0; it < 4; ++it) {
            int row  = w * 32 + it * 8 + srow_l;
            int slot = sslot ^ (row & 7);                  // pre-swizzled source slot
            const unsigned short* gA = A2 + (((size_t)(n0 + row)) << 8) + kc * 64 + slot * 8;
            gload16(gA, (char*)sA + (w * 4096 + it * 1024));
            const unsigned short* gB = B2T + (((size_t)(m0 + row)) << 8) + kc * 64 + slot * 8;
            gload16(gB, (char*)sB + (w * 4096 + it * 1024));
        }
        __syncthreads();   // drains vmcnt before reads

        short8v aF[4][2], bF[4][2];
        #pragma unroll
        for (int mi = 0; mi < 4; ++mi) {
            int row = wrow + mi * 16 + c;
            #pragma unroll
            for (int kb = 0; kb < 2; ++kb) {
                int koff = (kb * 64 + g * 16) ^ ((row & 7) << 4);
                aF[mi][kb] = *(const short8v*)((const char*)sA + row * 128 + koff);
            }
        }
        #pragma unroll
        for (int nj = 0; nj < 4; ++nj) {
            int row = wcol + nj * 16 + c;
            #pragma unroll
            for (int kb = 0; kb < 2; ++kb) {
                int koff = (kb * 64 + g * 16) ^ ((row & 7) << 4);
                bF[nj][kb] = *(const short8v*)((const char*)sB + row * 128 + koff);
            }
        }

        #pragma unroll
        for (int mi = 0; mi < 4; ++mi)
            #pragma unroll
            for (int nj = 0; nj < 4; ++nj)
                #pragma unroll
                for (int kb = 0; kb < 2; ++kb)
                    acc[mi][nj] = __builtin_amdgcn_mfma_f32_16x16x32_bf16(
                        aF[mi][kb], bF[nj][kb], acc[mi][nj], 0, 0, 0);

        __syncthreads();
    }

    // Epilogue. D layout: n-row = 4*g + reg, m-col = c within each 16x16 fragment.
    #pragma unroll
    for (int mi = 0; mi < 4; ++mi) {
        #pragma unroll
        for (int i = 0; i < 4; ++i) {
            int n = n0 + wrow + mi * 16 + 4 * g + i;
            int d = dom[n];
            const float* bp = bias + (size_t)d * M;

            if (WRITE == 0) {
                float vv[4];
                float mx = -3.0e38f;
                #pragma unroll
                for (int nj = 0; nj < 4; ++nj) {
                    int m = m0 + wcol + nj * 16 + c;
                    float bv = (m < M) ? bp[m] : 0.f;
                    vv[nj] = (m < M) ? (acc[mi][nj][i] + bv) : -3.0e38f;
                    mx = fmaxf(mx, vv[nj]);
                }
                #pragma unroll
                for (int msk = 1; msk < 16; msk <<= 1)
                    mx = fmaxf(mx, __shfl_xor(mx, msk));
                float sm = 0.f;
                #pragma unroll
                for (int nj = 0; nj < 4; ++nj)
                    sm += __expf(vv[nj] - mx);
                #pragma unroll
                for (int msk = 1; msk < 16; msk <<= 1)
                    sm += __shfl_xor(sm, msk);
                if (c == 0) {
                    int chunk = blockIdx.x * 2 + (wcol >> 6);
                    pmax[(size_t)n * PT + chunk] = mx;
                    psum[(size_t)n * PT + chunk] = sm;
                }
            } else {
                float o = lse[n];
                #pragma unroll
                for (int nj = 0; nj < 4; ++nj) {
                    int m = m0 + wcol + nj * 16 + c;
                    if (m < M)
                        out[(size_t)n * M + m] = acc[mi][nj][i] + bp[m] - o;
                }
            }
        }
    }
}

// ---------------------------------------------------------------------------
// reduce per-chunk partials -> per-row LSE.  1 wave per row, T <= 64 chunks.
// ---------------------------------------------------------------------------
__global__ __launch_bounds__(256) void lse_kernel(
    const float* __restrict__ pmax, const float* __restrict__ psum,
    float* __restrict__ lse, int T)
{
    const int lane = threadIdx.x & 63;
    const int wv = threadIdx.x >> 6;
    const int n = blockIdx.x * 4 + wv;

    float pm = (lane < T) ? pmax[(size_t)n * T + lane] : -3.0e38f;
    float ps = (lane < T) ? psum[(size_t)n * T + lane] : 0.f;

    float mx = pm;
    #pragma unroll
    for (int off = 1; off < 64; off <<= 1)
        mx = fmaxf(mx, __shfl_xor(mx, off));
    float s = ps * __expf(pm - mx);
    #pragma unroll
    for (int off = 1; off < 64; off <<= 1)
        s += __shfl_xor(s, off);
    if (lane == 0) lse[n] = mx + logf(s);
}

// ---------------------------------------------------------------------------
extern "C" void kernel_launch(void* const* d_in, const int* in_sizes, int n_in,
                              void* d_out, int out_size, void* d_ws, size_t ws_size,
                              hipStream_t stream) {
    const float* theta  = (const float*)d_in[0];
    const float* alpha0 = (const float*)d_in[1];
    const float* alpha1 = (const float*)d_in[2];
    const float* beta   = (const float*)d_in[3];
    const float* bias0  = (const float*)d_in[4];
    const float* bias1  = (const float*)d_in[5];
    const int*   dom    = (const int*)d_in[6];

    float* out0 = (float*)d_out;
    float* out1 = out0 + (size_t)PN * PM0;

    // workspace layout (bytes, 256-aligned)
    char* ws = (char*)d_ws;
    size_t off = 0;
    auto alloc = [&](size_t bytes) { char* p = ws + off; off = (off + bytes + 255) & ~(size_t)255; return p; };
    float* topic0          = (float*)alloc((size_t)PZ * PM0 * 4);       // 1.6 MB
    float* topic1          = (float*)alloc((size_t)PZ * PM1 * 4);       // 0.8 MB
    unsigned short* A2     = (unsigned short*)alloc((size_t)PN * KP * 2);   // 8.4 MB
    unsigned short* B2T0   = (unsigned short*)alloc((size_t)4096 * KP * 2); // 2.1 MB
    unsigned short* B2T1   = (unsigned short*)alloc((size_t)2048 * KP * 2); // 1.05 MB
    float* pmax0           = (float*)alloc((size_t)PN * 64 * 4);        // 4.2 MB
    float* psum0           = (float*)alloc((size_t)PN * 64 * 4);
    float* pmax1           = (float*)alloc((size_t)PN * 32 * 4);        // 2.1 MB
    float* psum1           = (float*)alloc((size_t)PN * 32 * 4);
    float* lse0            = (float*)alloc((size_t)PN * 4);
    float* lse1            = (float*)alloc((size_t)PN * 4);

    // 1. topic GEMMs (f32, small)
    topic_kernel<<<dim3(63, 5), 256, 0, stream>>>(alpha0, beta, topic0, PM0);
    topic_kernel<<<dim3(32, 5), 256, 0, stream>>>(alpha1, beta, topic1, PM1);

    // 2. bf16 packing
    prep_theta_kernel<<<PN, 256, 0, stream>>>(theta, A2);
    prep_topicT_kernel<<<4096, 256, 0, stream>>>(topic0, B2T0, PM0);
    prep_topicT_kernel<<<2048, 256, 0, stream>>>(topic1, B2T1, PM1);

    // 3. pass A: partial max / sumexp
    mfma_pass<0><<<dim3(32, 128), 256, 0, stream>>>(
        A2, B2T0, bias0, dom, nullptr, nullptr, pmax0, psum0, PM0, 64);
    mfma_pass<0><<<dim3(16, 128), 256, 0, stream>>>(
        A2, B2T1, bias1, dom, nullptr, nullptr, pmax1, psum1, PM1, 32);

    // 4. per-row LSE
    lse_kernel<<<dim3(PN / 4), 256, 0, stream>>>(pmax0, psum0, lse0, 64);
    lse_kernel<<<dim3(PN / 4), 256, 0, stream>>>(pmax1, psum1, lse1, 32);

    // 5. pass B: recompute + write out
    mfma_pass<1><<<dim3(32, 128), 256, 0, stream>>>(
        A2, B2T0, bias0, dom, lse0, out0, nullptr, nullptr, PM0, 64);
    mfma_pass<1><<<dim3(16, 128), 256, 0, stream>>>(
        A2, B2T1, bias1, dom, lse1, out1, nullptr, nullptr, PM1, 32);
}

// Round 3
// 409.262 us; speedup vs baseline: 3.3481x; 1.3309x over previous
//
#include <hip/hip_runtime.h>
#include <hip/hip_bf16.h>

// Problem constants
#define PN 16384
#define PZ 100
#define PE 400
#define PM0 4000
#define PM1 2000
#define KP 128            // packed K: [0,100) = f16 data, [100,128) = zero
#define MPAD 6144         // 4096 (M0 seg) + 2048 (M1 seg)

typedef __attribute__((ext_vector_type(8))) _Float16 half8v;
typedef __attribute__((ext_vector_type(4))) float floatx4;
typedef __attribute__((ext_vector_type(4))) unsigned int uint4v;

__device__ __forceinline__ void gload16(const void* g, void* l) {
    __builtin_amdgcn_global_load_lds(
        (const __attribute__((address_space(1))) void*)g,
        (__attribute__((address_space(3))) void*)l, 16, 0, 0);
}

// ---------------------------------------------------------------------------
// zero-fill (16B granular)
// ---------------------------------------------------------------------------
__global__ __launch_bounds__(256) void fill_kernel(uint4v* __restrict__ p, int n16)
{
    int i = blockIdx.x * 256 + threadIdx.x;
    if (i < n16) p[i] = (uint4v){0u, 0u, 0u, 0u};
}

// ---------------------------------------------------------------------------
// topic: b2t[m][z] = f16( sum_e beta[z][e] * alpha[m][e] )  -- transposed f16
// grid.x = m-tile (64), grid.y = z-group (20 z), block 256 = 64 m x 4 zt x 5 z
// ---------------------------------------------------------------------------
__global__ __launch_bounds__(256) void topic_kernel(
    const float* __restrict__ alpha, const float* __restrict__ beta,
    _Float16* __restrict__ b2t, int M)
{
    __shared__ float sA[64][201];
    const int tid = threadIdx.x;
    const int ml = tid & 63;
    const int zt = tid >> 6;
    const int m0 = blockIdx.x * 64;
    const int z0 = blockIdx.y * 20 + zt * 5;

    float acc[5] = {0.f, 0.f, 0.f, 0.f, 0.f};

    for (int ec = 0; ec < 2; ++ec) {
        #pragma unroll
        for (int l = 0; l < 50; ++l) {
            int idx = tid + l * 256;
            int mr = idx / 200;
            int e  = idx - mr * 200;
            int m  = m0 + mr;
            sA[mr][e] = (m < M) ? alpha[(size_t)m * PE + ec * 200 + e] : 0.f;
        }
        __syncthreads();
        const float* bz = beta + (size_t)z0 * PE + ec * 200;
        #pragma unroll 4
        for (int e = 0; e < 200; ++e) {
            float a = sA[ml][e];
            #pragma unroll
            for (int zi = 0; zi < 5; ++zi)
                acc[zi] = fmaf(bz[zi * PE + e], a, acc[zi]);
        }
        __syncthreads();
    }
    int m = m0 + ml;
    if (m < M) {
        #pragma unroll
        for (int zi = 0; zi < 5; ++zi)
            b2t[(size_t)m * KP + (z0 + zi)] = (_Float16)acc[zi];
    }
}

// ---------------------------------------------------------------------------
// prep: A2[n][k] f16 : k<100 -> f16(theta[n][k]), else 0
// ---------------------------------------------------------------------------
__global__ __launch_bounds__(128) void prep_theta_kernel(
    const float* __restrict__ theta, _Float16* __restrict__ A2)
{
    const int n = blockIdx.x;
    const int k = threadIdx.x;
    _Float16 h = (_Float16)0.f;
    if (k < 100) h = (_Float16)theta[(size_t)n * PZ + k];
    A2[(size_t)n * KP + k] = h;
}

// ---------------------------------------------------------------------------
// Main MFMA GEMM: logit[n][m] = sum_k A2[n][k]*B2T[m][k], f16 in, f16 out.
// 128x128 tile, 4 waves (2x2), 16x16x32_f16, K=128 in 2 steps of 64.
// Both-sides XOR swizzle: linear LDS dest (global_load_lds), pre-swizzled
// global source slot, matching swizzled ds_read.
// ---------------------------------------------------------------------------
__global__ __launch_bounds__(256) void gemm_kernel(
    const _Float16* __restrict__ A2,    // [PN][KP]
    const _Float16* __restrict__ B2T,   // [MPAD][KP]
    unsigned short* __restrict__ logit) // [PN][MPAD] f16 bits
{
    __shared__ __align__(1024) _Float16 sA[128 * 64];  // 16 KB (rows of 128 B)
    __shared__ __align__(1024) _Float16 sB[128 * 64];  // 16 KB

    const int tid  = threadIdx.x;
    const int w    = tid >> 6;
    const int ll   = tid & 63;
    const int wrow = (w & 1) * 64;
    const int wcol = (w >> 1) * 64;
    const int g    = ll >> 4;
    const int c    = ll & 15;
    const int n0   = blockIdx.y * 128;
    const int m0   = blockIdx.x * 128;

    floatx4 acc[4][4];
    #pragma unroll
    for (int i = 0; i < 4; ++i)
        #pragma unroll
        for (int j = 0; j < 4; ++j)
            acc[i][j] = (floatx4){0.f, 0.f, 0.f, 0.f};

    const int srow_l = ll >> 3;   // row within 8-row staging instr
    const int sslot  = ll & 7;    // dest 16B slot within 128B row

    for (int kc = 0; kc < 2; ++kc) {
        #pragma unroll
        for (int it = 0; it < 4; ++it) {
            int row  = w * 32 + it * 8 + srow_l;
            int slot = sslot ^ (row & 7);   // pre-swizzled source slot
            const _Float16* gA = A2 + ((size_t)(n0 + row)) * KP + kc * 64 + slot * 8;
            gload16(gA, (char*)sA + (w * 4096 + it * 1024));
            const _Float16* gB = B2T + ((size_t)(m0 + row)) * KP + kc * 64 + slot * 8;
            gload16(gB, (char*)sB + (w * 4096 + it * 1024));
        }
        __syncthreads();

        half8v aF[4][2], bF[4][2];
        #pragma unroll
        for (int mi = 0; mi < 4; ++mi) {
            int row = wrow + mi * 16 + c;
            #pragma unroll
            for (int kb = 0; kb < 2; ++kb) {
                int koff = (kb * 64 + g * 16) ^ ((row & 7) << 4);
                aF[mi][kb] = *(const half8v*)((const char*)sA + row * 128 + koff);
            }
        }
        #pragma unroll
        for (int nj = 0; nj < 4; ++nj) {
            int row = wcol + nj * 16 + c;
            #pragma unroll
            for (int kb = 0; kb < 2; ++kb) {
                int koff = (kb * 64 + g * 16) ^ ((row & 7) << 4);
                bF[nj][kb] = *(const half8v*)((const char*)sB + row * 128 + koff);
            }
        }

        #pragma unroll
        for (int mi = 0; mi < 4; ++mi)
            #pragma unroll
            for (int nj = 0; nj < 4; ++nj)
                #pragma unroll
                for (int kb = 0; kb < 2; ++kb)
                    acc[mi][nj] = __builtin_amdgcn_mfma_f32_16x16x32_f16(
                        aF[mi][kb], bF[nj][kb], acc[mi][nj], 0, 0, 0);

        __syncthreads();
    }

    // store raw f16 logits; pad columns/rows land in pad regions of ws
    #pragma unroll
    for (int mi = 0; mi < 4; ++mi) {
        #pragma unroll
        for (int i = 0; i < 4; ++i) {
            int n = n0 + wrow + mi * 16 + 4 * g + i;
            unsigned short* lp = logit + (size_t)n * MPAD + m0 + wcol + c;
            #pragma unroll
            for (int nj = 0; nj < 4; ++nj) {
                _Float16 h = (_Float16)acc[mi][nj][i];
                lp[nj * 16] = __builtin_bit_cast(unsigned short, h);
            }
        }
    }
}

// ---------------------------------------------------------------------------
// Fused LSE + bias + writeout. One wave per row; row logits in registers.
// out[n][m] = (logit[n][m] + bias[dom[n]][m]) - LSE_m(logit + bias)
// ---------------------------------------------------------------------------
template<int NCH>
__global__ __launch_bounds__(256) void lsewrite_kernel(
    const unsigned short* __restrict__ logit,  // [PN][MPAD] f16 bits
    const float* __restrict__ bias,            // [D][M]
    const int* __restrict__ dom,
    float* __restrict__ out, int M, int colOff)
{
    const int lane = threadIdx.x & 63;
    const int wv = threadIdx.x >> 6;
    const int n = blockIdx.x * 4 + wv;

    const unsigned short* lp = logit + (size_t)n * MPAD + colOff;
    const float* bp = bias + (size_t)dom[n] * M;
    float* op = out + (size_t)n * M;

    float v[NCH][8];
    float mx = -3.0e38f;

    #pragma unroll
    for (int ci = 0; ci < NCH; ++ci) {
        int base = ci * 512 + lane * 8;
        if (base < M) {
            half8v hv = *(const half8v*)&lp[base];
            float4 b0 = *(const float4*)&bp[base];
            float4 b1 = *(const float4*)&bp[base + 4];
            v[ci][0] = (float)hv[0] + b0.x;
            v[ci][1] = (float)hv[1] + b0.y;
            v[ci][2] = (float)hv[2] + b0.z;
            v[ci][3] = (float)hv[3] + b0.w;
            v[ci][4] = (float)hv[4] + b1.x;
            v[ci][5] = (float)hv[5] + b1.y;
            v[ci][6] = (float)hv[6] + b1.z;
            v[ci][7] = (float)hv[7] + b1.w;
            #pragma unroll
            for (int j = 0; j < 8; ++j)
                mx = fmaxf(mx, v[ci][j]);
        } else {
            #pragma unroll
            for (int j = 0; j < 8; ++j)
                v[ci][j] = -3.0e38f;
        }
    }

    #pragma unroll
    for (int off = 1; off < 64; off <<= 1)
        mx = fmaxf(mx, __shfl_xor(mx, off));

    float s = 0.f;
    #pragma unroll
    for (int ci = 0; ci < NCH; ++ci)
        #pragma unroll
        for (int j = 0; j < 8; ++j)
            s += __expf(v[ci][j] - mx);   // invalid: exp(-inf) = 0

    #pragma unroll
    for (int off = 1; off < 64; off <<= 1)
        s += __shfl_xor(s, off);

    const float lse = mx + __logf(s);

    #pragma unroll
    for (int ci = 0; ci < NCH; ++ci) {
        int base = ci * 512 + lane * 8;
        if (base < M) {
            float4 o0 = make_float4(v[ci][0] - lse, v[ci][1] - lse,
                                    v[ci][2] - lse, v[ci][3] - lse);
            float4 o1 = make_float4(v[ci][4] - lse, v[ci][5] - lse,
                                    v[ci][6] - lse, v[ci][7] - lse);
            *(float4*)&op[base] = o0;
            *(float4*)&op[base + 4] = o1;
        }
    }
}

// ---------------------------------------------------------------------------
extern "C" void kernel_launch(void* const* d_in, const int* in_sizes, int n_in,
                              void* d_out, int out_size, void* d_ws, size_t ws_size,
                              hipStream_t stream) {
    const float* theta  = (const float*)d_in[0];
    const float* alpha0 = (const float*)d_in[1];
    const float* alpha1 = (const float*)d_in[2];
    const float* beta   = (const float*)d_in[3];
    const float* bias0  = (const float*)d_in[4];
    const float* bias1  = (const float*)d_in[5];
    const int*   dom    = (const int*)d_in[6];

    float* out0 = (float*)d_out;
    float* out1 = out0 + (size_t)PN * PM0;

    char* ws = (char*)d_ws;
    size_t off = 0;
    auto alloc = [&](size_t bytes) { char* p = ws + off; off = (off + bytes + 255) & ~(size_t)255; return p; };
    _Float16* A2          = (_Float16*)alloc((size_t)PN * KP * 2);        // 4.2 MB
    _Float16* B2T         = (_Float16*)alloc((size_t)MPAD * KP * 2);      // 1.6 MB
    unsigned short* logit = (unsigned short*)alloc((size_t)PN * MPAD * 2);// 201 MB

    // 1. zero B2T (pad rows/cols)
    {
        int n16 = MPAD * KP * 2 / 16;
        fill_kernel<<<(n16 + 255) / 256, 256, 0, stream>>>((uint4v*)B2T, n16);
    }

    // 2. topic -> B2T f16 (transposed), M0 segment then M1 segment
    topic_kernel<<<dim3(63, 5), 256, 0, stream>>>(alpha0, beta, B2T, PM0);
    topic_kernel<<<dim3(32, 5), 256, 0, stream>>>(alpha1, beta, B2T + (size_t)4096 * KP, PM1);

    // 3. theta -> A2 f16
    prep_theta_kernel<<<PN, 128, 0, stream>>>(theta, A2);

    // 4. single MFMA GEMM -> raw f16 logits
    gemm_kernel<<<dim3(MPAD / 128, PN / 128), 256, 0, stream>>>(A2, B2T, logit);

    // 5. fused LSE + bias + writeout
    lsewrite_kernel<8><<<PN / 4, 256, 0, stream>>>(logit, bias0, dom, out0, PM0, 0);
    lsewrite_kernel<4><<<PN / 4, 256, 0, stream>>>(logit, bias1, dom, out1, PM1, 4096);
}